// Round 6
// baseline (105.687 us; speedup 1.0000x reference)
//
#include <hip/hip_runtime.h>
#include <hip/hip_bf16.h>

typedef __attribute__((ext_vector_type(8))) short short8;
typedef __attribute__((ext_vector_type(4))) float f32x4;

namespace {
constexpr int Nc  = 2048;   // N
constexpr int NXc = 4096;   // 2N
constexpr int Pc  = 64;
constexpr int Mc  = 4;
constexpr int Dc  = 256;
constexpr int BH  = 16;
constexpr int TN  = 128;    // n-rows per block
constexpr int LDW = 72;     // padded LDS row stride (bf16)
constexpr float LOG2E = 1.4426950408889634f;
}

__device__ inline float fexp2(float x) {
#if __has_builtin(__builtin_amdgcn_exp2f)
  return __builtin_amdgcn_exp2f(x);
#else
  return exp2f(x);
#endif
}

__device__ inline unsigned int bfpack(float a, float b) {
  union { __hip_bfloat162 h; unsigned int u; } cv;
  cv.h = __float22bfloat162_rn(make_float2(a, b));
  return cv.u;
}

// Gather-only pre-pass: Wb[bh][m*256+d][64] = bf16( LOG2E * X[bh][SK[b,m,d]][:] )
__global__ __launch_bounds__(256) void prepass_kernel(
    const float* __restrict__ Q, const float* __restrict__ K,
    const int* __restrict__ SK, __hip_bfloat16* __restrict__ Wb)
{
  const int t  = blockIdx.x * 256 + threadIdx.x;
  const int q  = t & 7;
  const int r  = t >> 3;            // 0..16383
  const int bh = r >> 10;
  const int md = r & 1023;
  const int b  = bh >> 3;
  const int idx = SK[b * (Mc * Dc) + md];
  const float* src = (idx < Nc) ? (Q + ((size_t)bh * Nc + idx) * Pc)
                                : (K + ((size_t)bh * Nc + (idx - Nc)) * Pc);
  const f32x4* s4 = (const f32x4*)(src + q * 8);
  f32x4 f0 = s4[0], f1 = s4[1];
  uint4 u;
  u.x = bfpack(f0.x * LOG2E, f0.y * LOG2E);
  u.y = bfpack(f0.z * LOG2E, f0.w * LOG2E);
  u.z = bfpack(f1.x * LOG2E, f1.y * LOG2E);
  u.w = bfpack(f1.z * LOG2E, f1.w * LOG2E);
  *(uint4*)(Wb + (size_t)r * Pc + q * 8) = u;
}

// Main: block = 128 n-rows x 256 d, one bh. W streamed through double-buffered
// LDS; each wave owns a 16-row d-slice of the 64-row W chunk (A-frag = 2
// ds_read_b128/phase) and holds all 128 n-rows as register B-frags (8 tiles).
// MFMA: A = W (d), B = X (n) => lane's 4 C regs = 4 consecutive d.
__global__ __launch_bounds__(256, 2) void sketch_main(
    const float* __restrict__ Q, const float* __restrict__ K,
    const __hip_bfloat16* __restrict__ Wb,
    const float* __restrict__ SGN, float* __restrict__ OUT)
{
  __shared__ __hip_bfloat16 Ws[2][64][LDW];  // 18432 B
  __shared__ float Ss[Mc * Dc];              //  4096 B

  const int t    = threadIdx.x;
  const int lane = t & 63;
  const int wv   = t >> 6;       // wave owns d-slice [wv*16, wv*16+16) of chunk
  const int brow = lane & 15;
  const int q    = lane >> 4;
  const int bh   = blockIdx.y;
  const int n0   = blockIdx.x * TN;

  for (int i = t; i < Mc * Dc; i += 256) Ss[i] = SGN[i];

  // X B-frags: 8 tiles of 16 n-rows. lane: row = tj*16+brow, k = kh*32+q*8+j
  short8 bx[8][2];
  {
    const float* xbase = (n0 < Nc) ? (Q + ((size_t)bh * Nc + n0) * Pc)
                                   : (K + ((size_t)bh * Nc + (n0 - Nc)) * Pc);
    #pragma unroll
    for (int tj = 0; tj < 8; ++tj) {
      const float* xr = xbase + (size_t)(tj * 16 + brow) * Pc + q * 8;
      f32x4 f0 = *(const f32x4*)xr;
      f32x4 f1 = *(const f32x4*)(xr + 4);
      f32x4 f2 = *(const f32x4*)(xr + 32);
      f32x4 f3 = *(const f32x4*)(xr + 36);
      union { short8 s; uint4 u; } c0, c1;
      c0.u.x = bfpack(f0.x, f0.y); c0.u.y = bfpack(f0.z, f0.w);
      c0.u.z = bfpack(f1.x, f1.y); c0.u.w = bfpack(f1.z, f1.w);
      c1.u.x = bfpack(f2.x, f2.y); c1.u.y = bfpack(f2.z, f2.w);
      c1.u.z = bfpack(f3.x, f3.y); c1.u.w = bfpack(f3.z, f3.w);
      bx[tj][0] = c0.s; bx[tj][1] = c1.s;
    }
  }

  const __hip_bfloat16* wbase = Wb + (size_t)bh * (Mc * Dc) * Pc;
  const int tr = t >> 2;        // staging row 0..63
  const int tq = t & 3;         // 16-elem quarter

  // phase p = dc*4 + m; W chunk rows [crow(p), crow(p)+64) of the 1024
  auto crow = [](int p) { return (p & 3) * Dc + (p >> 2) * 64; };

  // preload chunk 0 into buf 0
  {
    const __hip_bfloat16* wp = wbase + (size_t)(crow(0) + tr) * Pc + tq * 16;
    uint4 wa = *(const uint4*)wp;
    uint4 wb = *(const uint4*)(wp + 8);
    *(uint4*)&Ws[0][tr][tq * 16]     = wa;
    *(uint4*)&Ws[0][tr][tq * 16 + 8] = wb;
  }
  __syncthreads();

  f32x4 AS[8];
  #pragma unroll
  for (int tj = 0; tj < 8; ++tj) AS[tj] = (f32x4){0.f, 0.f, 0.f, 0.f};

  for (int p = 0; p < 16; ++p) {
    // issue next chunk's global loads early (overlap with compute)
    const int pn = (p < 15) ? p + 1 : 15;
    const __hip_bfloat16* wp = wbase + (size_t)(crow(pn) + tr) * Pc + tq * 16;
    uint4 wa = *(const uint4*)wp;
    uint4 wb = *(const uint4*)(wp + 8);

    const int buf = p & 1;
    const int m   = p & 3;
    const int dc  = p >> 2;

    // A-frag: this wave's d-slice; lane: row = wv*16+brow, k = kh*32+q*8+j
    short8 a0 = *(const short8*)&Ws[buf][wv * 16 + brow][q * 8];
    short8 a1 = *(const short8*)&Ws[buf][wv * 16 + brow][32 + q * 8];

    // sign for this wave's 4 d values (same for all n-tiles)
    const f32x4 sg = *(const f32x4*)&Ss[m * Dc + dc * 64 + wv * 16 + q * 4];

    #pragma unroll
    for (int tj = 0; tj < 8; ++tj) {
      f32x4 c = {0.f, 0.f, 0.f, 0.f};
      c = __builtin_amdgcn_mfma_f32_16x16x32_bf16(a0, bx[tj][0], c, 0, 0, 0);
      c = __builtin_amdgcn_mfma_f32_16x16x32_bf16(a1, bx[tj][1], c, 0, 0, 0);
      AS[tj].x = fmaf(sg.x, fexp2(c.x), AS[tj].x);
      AS[tj].y = fmaf(sg.y, fexp2(c.y), AS[tj].y);
      AS[tj].z = fmaf(sg.z, fexp2(c.z), AS[tj].z);
      AS[tj].w = fmaf(sg.w, fexp2(c.w), AS[tj].w);
    }

    if (m == 3) {
      // store: n = n0 + tj*16 + brow, d = dc*64 + wv*16 + q*4 + reg (cached)
      float* obase = OUT + ((size_t)bh * NXc + n0) * Dc + dc * 64 + wv * 16 + q * 4;
      #pragma unroll
      for (int tj = 0; tj < 8; ++tj) {
        *(f32x4*)(obase + (size_t)(tj * 16 + brow) * Dc) = AS[tj];
        AS[tj] = (f32x4){0.f, 0.f, 0.f, 0.f};
      }
    }

    // stage next chunk into the other buffer
    *(uint4*)&Ws[buf ^ 1][tr][tq * 16]     = wa;
    *(uint4*)&Ws[buf ^ 1][tr][tq * 16 + 8] = wb;
    __syncthreads();
  }
}

extern "C" void kernel_launch(void* const* d_in, const int* in_sizes, int n_in,
                              void* d_out, int out_size, void* d_ws, size_t ws_size,
                              hipStream_t stream) {
  (void)in_sizes; (void)n_in; (void)out_size; (void)ws_size;
  const float* Q   = (const float*)d_in[0];
  const float* K   = (const float*)d_in[1];
  const int*   SK  = (const int*)d_in[2];
  const float* SGN = (const float*)d_in[3];
  float* OUT = (float*)d_out;

  __hip_bfloat16* Wb = (__hip_bfloat16*)d_ws;  // 2 MiB

  prepass_kernel<<<dim3(512), dim3(256), 0, stream>>>(Q, K, SK, Wb);
  sketch_main<<<dim3(NXc / TN, BH), dim3(256), 0, stream>>>(Q, K, Wb, SGN, OUT);
}